// Round 3
// baseline (199.939 us; speedup 1.0000x reference)
//
#include <hip/hip_runtime.h>

#define Bn 512
#define Tn 512
#define Cn 64

// Inputs (setup_inputs order):
// 0: emissions (B,T,C) f32   1: tags (B,T) i32   2: mask (B,T) i32
// 3: transitions (C,C) f32   4: start_transitions (C) f32   5: end_transitions (C) f32
// Output: scalar f32 = mean_b(log_denominator - log_numerator)
//
// R8: meet-in-the-middle (validated R5/R7 structure) with a BROADCAST-FREE
// systolic dot engine:
//  - out[j] = sum_i a[i]*W[i][j] via DPP row_ror:r source rotations.
//    4 phases (v, v^16, v^32, v^48) x 16 rotations cover all 64 i per lane;
//    weights are pre-permuted per lane so no cross-lane broadcast is needed.
//  - per step: 64 v_fmac_f32(dpp) + 2 ds_swizzle + 1 shfl_xor, 8 acc chains.
//    R5/R7 burned ~8-10cy per broadcast (readlane hazards / bpermute latency);
//    this engine has zero broadcasts.
//  - exp(transitions) staged once in LDS (coalesced) so the per-lane permuted
//    weight gather is cheap for both row (bwd) and column (fwd) order.
//  - renorm every 4th step, DEFERRED (validated R6/R7): max/rcp/log off the
//    critical path; scale applied as one multiply in the next step.

template <int CTRL>
__device__ __forceinline__ float fmax_dpp(const float v) {
    const int o = __builtin_amdgcn_update_dpp(__float_as_int(v), __float_as_int(v),
                                              CTRL, 0xF, 0xF, false);
    return fmaxf(v, __int_as_float(o));
}

// Validated wave64 max: quad xor1, quad xor2, half-mirror, mirror,
// bcast15, bcast31 -> lane 63 holds the max; readlane broadcasts.
__device__ __forceinline__ float wave_max64(float v) {
    v = fmax_dpp<0x0B1>(v);
    v = fmax_dpp<0x04E>(v);
    v = fmax_dpp<0x141>(v);
    v = fmax_dpp<0x140>(v);
    v = fmax_dpp<0x142>(v);
    v = fmax_dpp<0x143>(v);
    return __int_as_float(__builtin_amdgcn_readlane(__float_as_int(v), 63));
}

// row_ror:R as a value op (combinable into v_fmac_f32_dpp by the backend).
template <int CTRL>
__device__ __forceinline__ float dppf(const float v) {
    return __int_as_float(__builtin_amdgcn_update_dpp(
        __float_as_int(v), __float_as_int(v), CTRL, 0xF, 0xF, false));
}

// One 16-rotation phase: A[r&7] += ror_r(vp) * wp[r], r = 0..15.
__device__ __forceinline__ void phase_acc(const float vp, const float* __restrict__ wp,
                                          float* __restrict__ A) {
    A[0] = fmaf(vp,              wp[0],  A[0]);
    A[1] = fmaf(dppf<0x121>(vp), wp[1],  A[1]);
    A[2] = fmaf(dppf<0x122>(vp), wp[2],  A[2]);
    A[3] = fmaf(dppf<0x123>(vp), wp[3],  A[3]);
    A[4] = fmaf(dppf<0x124>(vp), wp[4],  A[4]);
    A[5] = fmaf(dppf<0x125>(vp), wp[5],  A[5]);
    A[6] = fmaf(dppf<0x126>(vp), wp[6],  A[6]);
    A[7] = fmaf(dppf<0x127>(vp), wp[7],  A[7]);
    A[0] = fmaf(dppf<0x128>(vp), wp[8],  A[0]);
    A[1] = fmaf(dppf<0x129>(vp), wp[9],  A[1]);
    A[2] = fmaf(dppf<0x12A>(vp), wp[10], A[2]);
    A[3] = fmaf(dppf<0x12B>(vp), wp[11], A[3]);
    A[4] = fmaf(dppf<0x12C>(vp), wp[12], A[4]);
    A[5] = fmaf(dppf<0x12D>(vp), wp[13], A[5]);
    A[6] = fmaf(dppf<0x12E>(vp), wp[14], A[6]);
    A[7] = fmaf(dppf<0x12F>(vp), wp[15], A[7]);
}

// Broadcast-free dot: s[j] = sum_i v[i] * w_perm[i], with w pre-permuted as
// w[p*16+r] = W[ ((j&48)^(16p)) | ((j+r)&15) ][j]  (fwd)  or row-major (bwd).
__device__ __forceinline__ float systolic_dot(const float v, const float* __restrict__ w) {
    const float v16 = __int_as_float(__builtin_amdgcn_ds_swizzle(__float_as_int(v), 0x401F));
    const float v32 = __shfl_xor(v, 32, 64);
    const float v48 = __int_as_float(__builtin_amdgcn_ds_swizzle(__float_as_int(v32), 0x401F));

    float A[8];
    A[0] = v               * w[0];
    A[1] = dppf<0x121>(v)  * w[1];
    A[2] = dppf<0x122>(v)  * w[2];
    A[3] = dppf<0x123>(v)  * w[3];
    A[4] = dppf<0x124>(v)  * w[4];
    A[5] = dppf<0x125>(v)  * w[5];
    A[6] = dppf<0x126>(v)  * w[6];
    A[7] = dppf<0x127>(v)  * w[7];
    A[0] = fmaf(dppf<0x128>(v), w[8],  A[0]);
    A[1] = fmaf(dppf<0x129>(v), w[9],  A[1]);
    A[2] = fmaf(dppf<0x12A>(v), w[10], A[2]);
    A[3] = fmaf(dppf<0x12B>(v), w[11], A[3]);
    A[4] = fmaf(dppf<0x12C>(v), w[12], A[4]);
    A[5] = fmaf(dppf<0x12D>(v), w[13], A[5]);
    A[6] = fmaf(dppf<0x12E>(v), w[14], A[6]);
    A[7] = fmaf(dppf<0x12F>(v), w[15], A[7]);

    phase_acc(v16, w + 16, A);   // rows ^16
    phase_acc(v32, w + 32, A);   // rows ^32
    phase_acc(v48, w + 48, A);   // rows ^48

    return ((A[0] + A[1]) + (A[2] + A[3])) + ((A[4] + A[5]) + (A[6] + A[7]));
}

// blocks 0..511: forward chain bt (steps t=1..256) + numerator.
// blocks 512..1023: backward chain bt (factors u=511..257, 255 steps).
__global__ __launch_bounds__(64, 1) void crf_half_kernel(
    const float* __restrict__ emissions,
    const int*   __restrict__ tags,
    const int*   __restrict__ mask,
    const float* __restrict__ transitions,
    const float* __restrict__ start_t,
    const float* __restrict__ end_t,
    float*       __restrict__ ws_alpha,   // [Bn][Cn]
    float*       __restrict__ ws_beta,    // [Bn][Cn]
    float*       __restrict__ ws_lsF,     // [Bn]
    float*       __restrict__ ws_lsB,     // [Bn]
    float*       __restrict__ ws_num,     // [Bn]
    float*       __restrict__ out)
{
    const int  blk = blockIdx.x;
    const bool fwd = blk < Bn;
    const int  bt  = blk & (Bn - 1);
    const int  j   = threadIdx.x;

    if (blk == 0 && j == 0) out[0] = 0.f;   // replaces the zero kernel

    const float* em  = emissions + (size_t)bt * Tn * Cn + j;
    const float* em0 = emissions + (size_t)bt * Tn * Cn;
    const int*   mk  = mask + bt * Tn;
    const int*   tg  = tags + bt * Tn;

    // Stage exp(transitions) in LDS (coalesced load+write), so the per-lane
    // permuted weight gather below is an LDS gather, not a global scatter.
    __shared__ float lW[Cn * Cn];
#pragma unroll 8
    for (int i = 0; i < Cn; ++i)
        lW[i * Cn + j] = __expf(transitions[i * Cn + j]);
    __builtin_amdgcn_wave_barrier();

    // Per-lane systolic-permuted weights.
    float w[Cn];
    if (fwd) {
#pragma unroll
        for (int p = 0; p < 4; ++p)
#pragma unroll
            for (int r = 0; r < 16; ++r) {
                const int i = ((j & 48) ^ (p << 4)) | ((j + r) & 15);
                w[p * 16 + r] = lW[i * Cn + j];       // column j of expT
            }
    } else {
#pragma unroll
        for (int p = 0; p < 4; ++p)
#pragma unroll
            for (int r = 0; r < 16; ++r) {
                const int i = ((j & 48) ^ (p << 4)) | ((j + r) & 15);
                w[p * 16 + r] = lW[j * Cn + i];       // row j of expT
            }
    }

    if (fwd) {
        // ---------------- numerator (joint score), lanes stride over T -----
        float nsum = 0.f;
        int   mcnt = 0;
        for (int t = j; t < Tn; t += 64) {
            const int tag_t = tg[t];
            const int m_t   = mk[t];
            mcnt += m_t;
            if (t >= 1 && m_t) {
                const int tag_p = tg[t - 1];
                nsum += transitions[tag_p * Cn + tag_t] + em0[t * Cn + tag_t];
            }
        }
#pragma unroll
        for (int off = 32; off > 0; off >>= 1) {
            nsum += __shfl_xor(nsum, off, 64);
            mcnt += __shfl_xor(mcnt, off, 64);
        }

        // t = 0.
        float lp0 = start_t[j] + em[0];
        const float m0 = wave_max64(lp0);
        float log_scale = m0;
        float a_self = __expf(lp0 - m0);     // lane j holds alpha[j]
        float c_pend = 1.0f;                 // deferred renorm scale

        // Prefetch group 0 (t = 1..4).
        float cur_e[4];
        int   cur_m[4];
#pragma unroll
        for (int k = 0; k < 4; ++k) {
            cur_e[k] = em[(size_t)(1 + k) * Cn];
            cur_m[k] = mk[1 + k];
        }

        for (int g = 0; g < 64; ++g) {       // 64 groups x 4 = 256 steps
            float nxt_e[4];
            int   nxt_m[4];
#pragma unroll
            for (int k = 0; k < 4; ++k) {
                const int t = 4 * g + 5 + k;  // <= 260 < Tn, always valid
                nxt_e[k] = em[(size_t)t * Cn];
                nxt_m[k] = mk[t];
            }
            float ex[4];
#pragma unroll
            for (int k = 0; k < 4; ++k) ex[k] = __expf(cur_e[k]);

#pragma unroll
            for (int k = 0; k < 4; ++k) {
                float s = systolic_dot(a_self, w) * ex[k];
                if (!cur_m[k]) s = a_self;    // frozen step: alpha carries
                if (k == 0) {                 // apply deferred scale exactly once
                    s *= c_pend;
                    c_pend = 1.0f;
                }
                if (k == 3) {                 // renorm every 4th step (deferred)
                    const float mx = wave_max64(s);
                    c_pend = __builtin_amdgcn_rcpf(mx);
                    log_scale += __logf(mx);
                }
                a_self = s;
            }
#pragma unroll
            for (int k = 0; k < 4; ++k) {
                cur_e[k] = nxt_e[k];
                cur_m[k] = nxt_m[k];
            }
        }

        a_self *= c_pend;                     // flush pending scale
        ws_alpha[bt * Cn + j] = a_self;       // alpha_256
        if (j == 0) {
            ws_lsF[bt] = log_scale;
            const int t0 = tg[0];
            const int tl = tg[mcnt - 1];
            ws_num[bt] = start_t[t0] + em0[t0] + nsum + end_t[tl];
        }
    } else {
        // beta_511 = exp(end - max).
        float lp0 = end_t[j];
        const float m0 = wave_max64(lp0);
        float log_scale = m0;
        float b_self = __expf(lp0 - m0);      // lane j holds beta[j]
        float c_pend = 1.0f;

        // Step s applies factor at u = 511 - s (emissions/mask row u).
        // Prefetch group 0: s = 0..3 -> u = 511..508.
        float cur_e[4];
        int   cur_m[4];
#pragma unroll
        for (int k = 0; k < 4; ++k) {
            const int u = Tn - 1 - k;
            cur_e[k] = em[(size_t)u * Cn];
            cur_m[k] = mk[u];
        }

        for (int g = 0; g < 64; ++g) {        // steps s=4g+k, active while s<255
            float nxt_e[4];
            int   nxt_m[4];
#pragma unroll
            for (int k = 0; k < 4; ++k) {
                const int u = Tn - 5 - 4 * g - k;  // >= 252 >= 0, always valid
                nxt_e[k] = em[(size_t)u * Cn];
                nxt_m[k] = mk[u];
            }
            float ex[4];
#pragma unroll
            for (int k = 0; k < 4; ++k) ex[k] = __expf(cur_e[k]);

#pragma unroll
            for (int k = 0; k < 4; ++k) {
                const int s_idx = 4 * g + k;
                if (s_idx < Tn / 2 - 1) {     // 255 steps
                    const float wval = b_self * ex[k];   // e_u[j] * beta[j]
                    float s = systolic_dot(wval, w);
                    if (!cur_m[k]) s = b_self;   // frozen step: beta carries
                    if (k == 0) {
                        s *= c_pend;
                        c_pend = 1.0f;
                    }
                    if (k == 3) {
                        const float mx = wave_max64(s);
                        c_pend = __builtin_amdgcn_rcpf(mx);
                        log_scale += __logf(mx);
                    }
                    b_self = s;
                }
            }
#pragma unroll
            for (int k = 0; k < 4; ++k) {
                cur_e[k] = nxt_e[k];
                cur_m[k] = nxt_m[k];
            }
        }

        b_self *= c_pend;                     // flush pending scale
        ws_beta[bt * Cn + j] = b_self;        // beta_256
        if (j == 0) ws_lsB[bt] = log_scale;
    }
}

// Per chain: denom = lsF + lsB + log(sum_i alpha[i]*beta[i]); mean-reduce.
// 32 blocks x 16 waves; one chain per wave; one atomicAdd per block.
__global__ __launch_bounds__(1024) void crf_combine_kernel(
    const float* __restrict__ ws_alpha,
    const float* __restrict__ ws_beta,
    const float* __restrict__ ws_lsF,
    const float* __restrict__ ws_lsB,
    const float* __restrict__ ws_num,
    float*       __restrict__ out)
{
    const int wv = threadIdx.x >> 6;          // wave 0..15
    const int j  = threadIdx.x & 63;
    const int bt = blockIdx.x * 16 + wv;

    __shared__ float part[16];

    float v = ws_alpha[bt * Cn + j] * ws_beta[bt * Cn + j];
#pragma unroll
    for (int off = 32; off > 0; off >>= 1) v += __shfl_xor(v, off, 64);
    if (j == 0) {
        part[wv] = ws_lsF[bt] + ws_lsB[bt] + __logf(v) - ws_num[bt];
    }
    __syncthreads();
    if (threadIdx.x < 64) {
        float p = (j < 16) ? part[j] : 0.f;
#pragma unroll
        for (int off = 32; off > 0; off >>= 1) p += __shfl_xor(p, off, 64);
        if (j == 0) atomicAdd(out, p * (1.0f / Bn));
    }
}

extern "C" void kernel_launch(void* const* d_in, const int* in_sizes, int n_in,
                              void* d_out, int out_size, void* d_ws, size_t ws_size,
                              hipStream_t stream)
{
    const float* emissions   = (const float*)d_in[0];
    const int*   tags        = (const int*)d_in[1];
    const int*   mask        = (const int*)d_in[2];
    const float* transitions = (const float*)d_in[3];
    const float* start_t     = (const float*)d_in[4];
    const float* end_t       = (const float*)d_in[5];

    float* ws       = (float*)d_ws;
    float* ws_alpha = ws;                       // 512*64
    float* ws_beta  = ws_alpha + Bn * Cn;       // 512*64
    float* ws_lsF   = ws_beta + Bn * Cn;        // 512
    float* ws_lsB   = ws_lsF + Bn;              // 512
    float* ws_num   = ws_lsB + Bn;              // 512

    crf_half_kernel<<<2 * Bn, Cn, 0, stream>>>(emissions, tags, mask, transitions,
                                               start_t, end_t,
                                               ws_alpha, ws_beta, ws_lsF, ws_lsB, ws_num,
                                               (float*)d_out);
    crf_combine_kernel<<<Bn / 16, 1024, 0, stream>>>(ws_alpha, ws_beta, ws_lsF, ws_lsB,
                                                     ws_num, (float*)d_out);
}

// Round 4
// 198.720 us; speedup vs baseline: 1.0061x; 1.0061x over previous
//
#include <hip/hip_runtime.h>

#define Bn 512
#define Tn 512
#define Cn 64

// Inputs (setup_inputs order):
// 0: emissions (B,T,C) f32   1: tags (B,T) i32   2: mask (B,T) i32
// 3: transitions (C,C) f32   4: start_transitions (C) f32   5: end_transitions (C) f32
// Output: scalar f32 = mean_b(log_denominator - log_numerator)
//
// R9 = R8 (broadcast-free systolic DPP dot, validated numerics) + ONE change:
//   __attribute__((amdgpu_waves_per_eu(1,1))) on crf_half_kernel.
// R5/R7/R8 all capped at VGPR_Count 52-76: the allocator targeted multi-wave
// occupancy and parked the 64 exp(transitions) weights in AGPRs, paying
// v_accvgpr_read shuttles on EVERY fma operand (~250 extra instrs/step).
// Grid is exactly 1024 waves on 1024 SIMDs, so >1 wave/SIMD is unreachable;
// pinning waves/EU to 1 gives the full 512-VGPR budget at zero occupancy cost.

template <int CTRL>
__device__ __forceinline__ float fmax_dpp(const float v) {
    const int o = __builtin_amdgcn_update_dpp(__float_as_int(v), __float_as_int(v),
                                              CTRL, 0xF, 0xF, false);
    return fmaxf(v, __int_as_float(o));
}

// Validated wave64 max: quad xor1, quad xor2, half-mirror, mirror,
// bcast15, bcast31 -> lane 63 holds the max; readlane broadcasts.
__device__ __forceinline__ float wave_max64(float v) {
    v = fmax_dpp<0x0B1>(v);
    v = fmax_dpp<0x04E>(v);
    v = fmax_dpp<0x141>(v);
    v = fmax_dpp<0x140>(v);
    v = fmax_dpp<0x142>(v);
    v = fmax_dpp<0x143>(v);
    return __int_as_float(__builtin_amdgcn_readlane(__float_as_int(v), 63));
}

// row_ror:R as a value op (single-use -> GCNDPPCombine folds into v_fmac_f32_dpp).
template <int CTRL>
__device__ __forceinline__ float dppf(const float v) {
    return __int_as_float(__builtin_amdgcn_update_dpp(
        __float_as_int(v), __float_as_int(v), CTRL, 0xF, 0xF, false));
}

// One 16-rotation phase: A[r&7] += ror_r(vp) * wp[r], r = 0..15.
__device__ __forceinline__ void phase_acc(const float vp, const float* __restrict__ wp,
                                          float* __restrict__ A) {
    A[0] = fmaf(vp,              wp[0],  A[0]);
    A[1] = fmaf(dppf<0x121>(vp), wp[1],  A[1]);
    A[2] = fmaf(dppf<0x122>(vp), wp[2],  A[2]);
    A[3] = fmaf(dppf<0x123>(vp), wp[3],  A[3]);
    A[4] = fmaf(dppf<0x124>(vp), wp[4],  A[4]);
    A[5] = fmaf(dppf<0x125>(vp), wp[5],  A[5]);
    A[6] = fmaf(dppf<0x126>(vp), wp[6],  A[6]);
    A[7] = fmaf(dppf<0x127>(vp), wp[7],  A[7]);
    A[0] = fmaf(dppf<0x128>(vp), wp[8],  A[0]);
    A[1] = fmaf(dppf<0x129>(vp), wp[9],  A[1]);
    A[2] = fmaf(dppf<0x12A>(vp), wp[10], A[2]);
    A[3] = fmaf(dppf<0x12B>(vp), wp[11], A[3]);
    A[4] = fmaf(dppf<0x12C>(vp), wp[12], A[4]);
    A[5] = fmaf(dppf<0x12D>(vp), wp[13], A[5]);
    A[6] = fmaf(dppf<0x12E>(vp), wp[14], A[6]);
    A[7] = fmaf(dppf<0x12F>(vp), wp[15], A[7]);
}

// Broadcast-free dot: s[j] = sum_i v[i] * w_perm[i], with w pre-permuted as
// w[p*16+r] = W[ ((j&48)^(16p)) | ((j+r)&15) ][j]  (fwd)  or row-major (bwd).
__device__ __forceinline__ float systolic_dot(const float v, const float* __restrict__ w) {
    const float v16 = __int_as_float(__builtin_amdgcn_ds_swizzle(__float_as_int(v), 0x401F));
    const float v32 = __shfl_xor(v, 32, 64);
    const float v48 = __int_as_float(__builtin_amdgcn_ds_swizzle(__float_as_int(v32), 0x401F));

    float A[8];
    A[0] = v               * w[0];
    A[1] = dppf<0x121>(v)  * w[1];
    A[2] = dppf<0x122>(v)  * w[2];
    A[3] = dppf<0x123>(v)  * w[3];
    A[4] = dppf<0x124>(v)  * w[4];
    A[5] = dppf<0x125>(v)  * w[5];
    A[6] = dppf<0x126>(v)  * w[6];
    A[7] = dppf<0x127>(v)  * w[7];
    A[0] = fmaf(dppf<0x128>(v), w[8],  A[0]);
    A[1] = fmaf(dppf<0x129>(v), w[9],  A[1]);
    A[2] = fmaf(dppf<0x12A>(v), w[10], A[2]);
    A[3] = fmaf(dppf<0x12B>(v), w[11], A[3]);
    A[4] = fmaf(dppf<0x12C>(v), w[12], A[4]);
    A[5] = fmaf(dppf<0x12D>(v), w[13], A[5]);
    A[6] = fmaf(dppf<0x12E>(v), w[14], A[6]);
    A[7] = fmaf(dppf<0x12F>(v), w[15], A[7]);

    phase_acc(v16, w + 16, A);   // rows ^16
    phase_acc(v32, w + 32, A);   // rows ^32
    phase_acc(v48, w + 48, A);   // rows ^48

    return ((A[0] + A[1]) + (A[2] + A[3])) + ((A[4] + A[5]) + (A[6] + A[7]));
}

// blocks 0..511: forward chain bt (steps t=1..256) + numerator.
// blocks 512..1023: backward chain bt (factors u=511..257, 255 steps).
__global__ __launch_bounds__(64)
__attribute__((amdgpu_waves_per_eu(1, 1)))
void crf_half_kernel(
    const float* __restrict__ emissions,
    const int*   __restrict__ tags,
    const int*   __restrict__ mask,
    const float* __restrict__ transitions,
    const float* __restrict__ start_t,
    const float* __restrict__ end_t,
    float*       __restrict__ ws_alpha,   // [Bn][Cn]
    float*       __restrict__ ws_beta,    // [Bn][Cn]
    float*       __restrict__ ws_lsF,     // [Bn]
    float*       __restrict__ ws_lsB,     // [Bn]
    float*       __restrict__ ws_num,     // [Bn]
    float*       __restrict__ out)
{
    const int  blk = blockIdx.x;
    const bool fwd = blk < Bn;
    const int  bt  = blk & (Bn - 1);
    const int  j   = threadIdx.x;

    if (blk == 0 && j == 0) out[0] = 0.f;   // replaces the zero kernel

    const float* em  = emissions + (size_t)bt * Tn * Cn + j;
    const float* em0 = emissions + (size_t)bt * Tn * Cn;
    const int*   mk  = mask + bt * Tn;
    const int*   tg  = tags + bt * Tn;

    // Stage exp(transitions) in LDS (coalesced load+write), so the per-lane
    // permuted weight gather below is an LDS gather, not a global scatter.
    __shared__ float lW[Cn * Cn];
#pragma unroll 8
    for (int i = 0; i < Cn; ++i)
        lW[i * Cn + j] = __expf(transitions[i * Cn + j]);
    __builtin_amdgcn_wave_barrier();

    // Per-lane systolic-permuted weights (resident in VGPRs with the 1,1 cap).
    float w[Cn];
    if (fwd) {
#pragma unroll
        for (int p = 0; p < 4; ++p)
#pragma unroll
            for (int r = 0; r < 16; ++r) {
                const int i = ((j & 48) ^ (p << 4)) | ((j + r) & 15);
                w[p * 16 + r] = lW[i * Cn + j];       // column j of expT
            }
    } else {
#pragma unroll
        for (int p = 0; p < 4; ++p)
#pragma unroll
            for (int r = 0; r < 16; ++r) {
                const int i = ((j & 48) ^ (p << 4)) | ((j + r) & 15);
                w[p * 16 + r] = lW[j * Cn + i];       // row j of expT
            }
    }

    if (fwd) {
        // ---------------- numerator (joint score), lanes stride over T -----
        float nsum = 0.f;
        int   mcnt = 0;
        for (int t = j; t < Tn; t += 64) {
            const int tag_t = tg[t];
            const int m_t   = mk[t];
            mcnt += m_t;
            if (t >= 1 && m_t) {
                const int tag_p = tg[t - 1];
                nsum += transitions[tag_p * Cn + tag_t] + em0[t * Cn + tag_t];
            }
        }
#pragma unroll
        for (int off = 32; off > 0; off >>= 1) {
            nsum += __shfl_xor(nsum, off, 64);
            mcnt += __shfl_xor(mcnt, off, 64);
        }

        // t = 0.
        float lp0 = start_t[j] + em[0];
        const float m0 = wave_max64(lp0);
        float log_scale = m0;
        float a_self = __expf(lp0 - m0);     // lane j holds alpha[j]
        float c_pend = 1.0f;                 // deferred renorm scale

        // Prefetch group 0 (t = 1..4).
        float cur_e[4];
        int   cur_m[4];
#pragma unroll
        for (int k = 0; k < 4; ++k) {
            cur_e[k] = em[(size_t)(1 + k) * Cn];
            cur_m[k] = mk[1 + k];
        }

        for (int g = 0; g < 64; ++g) {       // 64 groups x 4 = 256 steps
            float nxt_e[4];
            int   nxt_m[4];
#pragma unroll
            for (int k = 0; k < 4; ++k) {
                const int t = 4 * g + 5 + k;  // <= 260 < Tn, always valid
                nxt_e[k] = em[(size_t)t * Cn];
                nxt_m[k] = mk[t];
            }
            float ex[4];
#pragma unroll
            for (int k = 0; k < 4; ++k) ex[k] = __expf(cur_e[k]);

#pragma unroll
            for (int k = 0; k < 4; ++k) {
                float s = systolic_dot(a_self, w) * ex[k];
                if (!cur_m[k]) s = a_self;    // frozen step: alpha carries
                if (k == 0) {                 // apply deferred scale exactly once
                    s *= c_pend;
                    c_pend = 1.0f;
                }
                if (k == 3) {                 // renorm every 4th step (deferred)
                    const float mx = wave_max64(s);
                    c_pend = __builtin_amdgcn_rcpf(mx);
                    log_scale += __logf(mx);
                }
                a_self = s;
            }
#pragma unroll
            for (int k = 0; k < 4; ++k) {
                cur_e[k] = nxt_e[k];
                cur_m[k] = nxt_m[k];
            }
        }

        a_self *= c_pend;                     // flush pending scale
        ws_alpha[bt * Cn + j] = a_self;       // alpha_256
        if (j == 0) {
            ws_lsF[bt] = log_scale;
            const int t0 = tg[0];
            const int tl = tg[mcnt - 1];
            ws_num[bt] = start_t[t0] + em0[t0] + nsum + end_t[tl];
        }
    } else {
        // beta_511 = exp(end - max).
        float lp0 = end_t[j];
        const float m0 = wave_max64(lp0);
        float log_scale = m0;
        float b_self = __expf(lp0 - m0);      // lane j holds beta[j]
        float c_pend = 1.0f;

        // Step s applies factor at u = 511 - s (emissions/mask row u).
        // Prefetch group 0: s = 0..3 -> u = 511..508.
        float cur_e[4];
        int   cur_m[4];
#pragma unroll
        for (int k = 0; k < 4; ++k) {
            const int u = Tn - 1 - k;
            cur_e[k] = em[(size_t)u * Cn];
            cur_m[k] = mk[u];
        }

        for (int g = 0; g < 64; ++g) {        // steps s=4g+k, active while s<255
            float nxt_e[4];
            int   nxt_m[4];
#pragma unroll
            for (int k = 0; k < 4; ++k) {
                const int u = Tn - 5 - 4 * g - k;  // >= 252 >= 0, always valid
                nxt_e[k] = em[(size_t)u * Cn];
                nxt_m[k] = mk[u];
            }
            float ex[4];
#pragma unroll
            for (int k = 0; k < 4; ++k) ex[k] = __expf(cur_e[k]);

#pragma unroll
            for (int k = 0; k < 4; ++k) {
                const int s_idx = 4 * g + k;
                if (s_idx < Tn / 2 - 1) {     // 255 steps
                    const float wval = b_self * ex[k];   // e_u[j] * beta[j]
                    float s = systolic_dot(wval, w);
                    if (!cur_m[k]) s = b_self;   // frozen step: beta carries
                    if (k == 0) {
                        s *= c_pend;
                        c_pend = 1.0f;
                    }
                    if (k == 3) {
                        const float mx = wave_max64(s);
                        c_pend = __builtin_amdgcn_rcpf(mx);
                        log_scale += __logf(mx);
                    }
                    b_self = s;
                }
            }
#pragma unroll
            for (int k = 0; k < 4; ++k) {
                cur_e[k] = nxt_e[k];
                cur_m[k] = nxt_m[k];
            }
        }

        b_self *= c_pend;                     // flush pending scale
        ws_beta[bt * Cn + j] = b_self;        // beta_256
        if (j == 0) ws_lsB[bt] = log_scale;
    }
}

// Per chain: denom = lsF + lsB + log(sum_i alpha[i]*beta[i]); mean-reduce.
// 32 blocks x 16 waves; one chain per wave; one atomicAdd per block.
__global__ __launch_bounds__(1024) void crf_combine_kernel(
    const float* __restrict__ ws_alpha,
    const float* __restrict__ ws_beta,
    const float* __restrict__ ws_lsF,
    const float* __restrict__ ws_lsB,
    const float* __restrict__ ws_num,
    float*       __restrict__ out)
{
    const int wv = threadIdx.x >> 6;          // wave 0..15
    const int j  = threadIdx.x & 63;
    const int bt = blockIdx.x * 16 + wv;

    __shared__ float part[16];

    float v = ws_alpha[bt * Cn + j] * ws_beta[bt * Cn + j];
#pragma unroll
    for (int off = 32; off > 0; off >>= 1) v += __shfl_xor(v, off, 64);
    if (j == 0) {
        part[wv] = ws_lsF[bt] + ws_lsB[bt] + __logf(v) - ws_num[bt];
    }
    __syncthreads();
    if (threadIdx.x < 64) {
        float p = (j < 16) ? part[j] : 0.f;
#pragma unroll
        for (int off = 32; off > 0; off >>= 1) p += __shfl_xor(p, off, 64);
        if (j == 0) atomicAdd(out, p * (1.0f / Bn));
    }
}

extern "C" void kernel_launch(void* const* d_in, const int* in_sizes, int n_in,
                              void* d_out, int out_size, void* d_ws, size_t ws_size,
                              hipStream_t stream)
{
    const float* emissions   = (const float*)d_in[0];
    const int*   tags        = (const int*)d_in[1];
    const int*   mask        = (const int*)d_in[2];
    const float* transitions = (const float*)d_in[3];
    const float* start_t     = (const float*)d_in[4];
    const float* end_t       = (const float*)d_in[5];

    float* ws       = (float*)d_ws;
    float* ws_alpha = ws;                       // 512*64
    float* ws_beta  = ws_alpha + Bn * Cn;       // 512*64
    float* ws_lsF   = ws_beta + Bn * Cn;        // 512
    float* ws_lsB   = ws_lsF + Bn;              // 512
    float* ws_num   = ws_lsB + Bn;              // 512

    crf_half_kernel<<<2 * Bn, Cn, 0, stream>>>(emissions, tags, mask, transitions,
                                               start_t, end_t,
                                               ws_alpha, ws_beta, ws_lsF, ws_lsB, ws_num,
                                               (float*)d_out);
    crf_combine_kernel<<<Bn / 16, 1024, 0, stream>>>(ws_alpha, ws_beta, ws_lsF, ws_lsB,
                                                     ws_num, (float*)d_out);
}

// Round 5
// 180.970 us; speedup vs baseline: 1.1048x; 1.0981x over previous
//
#include <hip/hip_runtime.h>

#define Bn 512
#define Tn 512
#define Cn 64

// Inputs (setup_inputs order):
// 0: emissions (B,T,C) f32   1: tags (B,T) i32   2: mask (B,T) i32
// 3: transitions (C,C) f32   4: start_transitions (C) f32   5: end_transitions (C) f32
// Output: scalar f32 = mean_b(log_denominator - log_numerator)
//
// R10: R5's proven readlane dot engine (fastest measured: 85.7us) + removal of
// the three SHARED latency exposures that four different engines all paid:
//  1. #pragma unroll 1 on the main loop: body ~9KB stays hot in 32KB I$
//     (a fully/partially unrolled 64-group body streams cold from L2).
//  2. Ping-pong emission buffers, 2-group lead, loads issued AFTER the
//     buffer's last use: even a conservative loop-header vmcnt(0) has
//     ~2000cy of slack vs ~900cy HBM latency.
//  3. Mask bits pre-packed into wave-uniform ballot words: zero in-loop mask
//     loads; per-step bit is SALU select+shift off the VALU critical path.
// Numerics identical to validated R9 path (deferred renorm, mask-freeze,
// flush order). waves_per_eu(1,1) kept (full VGPR budget, zero occupancy cost
// at 1024 waves on 1024 SIMDs).

template <int CTRL>
__device__ __forceinline__ float fmax_dpp(const float v) {
    const int o = __builtin_amdgcn_update_dpp(__float_as_int(v), __float_as_int(v),
                                              CTRL, 0xF, 0xF, false);
    return fmaxf(v, __int_as_float(o));
}

// Validated wave64 max: quad xor1, quad xor2, half-mirror, mirror,
// bcast15, bcast31 -> lane 63 holds the max; readlane broadcasts.
__device__ __forceinline__ float wave_max64(float v) {
    v = fmax_dpp<0x0B1>(v);
    v = fmax_dpp<0x04E>(v);
    v = fmax_dpp<0x141>(v);
    v = fmax_dpp<0x140>(v);
    v = fmax_dpp<0x142>(v);
    v = fmax_dpp<0x143>(v);
    return __int_as_float(__builtin_amdgcn_readlane(__float_as_int(v), 63));
}

// R5's validated broadcast-dot: s = sum_i bcast(lane i of a) * w[i].
__device__ __forceinline__ float bcast_dot64(const float a, const float* __restrict__ w) {
    const int ai = __float_as_int(a);
    float acc0 = 0.f, acc1 = 0.f, acc2 = 0.f, acc3 = 0.f;
#pragma unroll
    for (int i = 0; i < Cn; i += 4) {
        const float b0 = __int_as_float(__builtin_amdgcn_readlane(ai, i + 0));
        const float b1 = __int_as_float(__builtin_amdgcn_readlane(ai, i + 1));
        const float b2 = __int_as_float(__builtin_amdgcn_readlane(ai, i + 2));
        const float b3 = __int_as_float(__builtin_amdgcn_readlane(ai, i + 3));
        acc0 = fmaf(b0, w[i + 0], acc0);
        acc1 = fmaf(b1, w[i + 1], acc1);
        acc2 = fmaf(b2, w[i + 2], acc2);
        acc3 = fmaf(b3, w[i + 3], acc3);
    }
    return (acc0 + acc1) + (acc2 + acc3);
}

// blocks 0..511: forward chain bt (steps t=1..256) + numerator.
// blocks 512..1023: backward chain bt (factors u=511..257, 255 steps).
__global__ __launch_bounds__(64)
__attribute__((amdgpu_waves_per_eu(1, 1)))
void crf_half_kernel(
    const float* __restrict__ emissions,
    const int*   __restrict__ tags,
    const int*   __restrict__ mask,
    const float* __restrict__ transitions,
    const float* __restrict__ start_t,
    const float* __restrict__ end_t,
    float*       __restrict__ ws_alpha,   // [Bn][Cn]
    float*       __restrict__ ws_beta,    // [Bn][Cn]
    float*       __restrict__ ws_lsF,     // [Bn]
    float*       __restrict__ ws_lsB,     // [Bn]
    float*       __restrict__ ws_num,     // [Bn]
    float*       __restrict__ out)
{
    const int  blk = blockIdx.x;
    const bool fwd = blk < Bn;
    const int  bt  = blk & (Bn - 1);
    const int  j   = threadIdx.x;

    if (blk == 0 && j == 0) out[0] = 0.f;   // fold the zero kernel

    const float* em  = emissions + (size_t)bt * Tn * Cn + j;
    const float* em0 = emissions + (size_t)bt * Tn * Cn;
    const int*   mk  = mask + bt * Tn;
    const int*   tg  = tags + bt * Tn;

    if (fwd) {
        // ---- numerator + ballot-pack mask windows 0..4 (t = 0..319) ------
        float nsum = 0.f;
        int   mcnt = 0;
        unsigned long long bal0 = 0, bal1 = 0, bal2 = 0, bal3 = 0, bal4 = 0;
#pragma unroll
        for (int it = 0; it < 8; ++it) {
            const int t     = it * 64 + j;
            const int tag_t = tg[t];
            const int m_t   = mk[t];
            const unsigned long long b = __ballot(m_t != 0);
            if      (it == 0) bal0 = b;
            else if (it == 1) bal1 = b;
            else if (it == 2) bal2 = b;
            else if (it == 3) bal3 = b;
            else if (it == 4) bal4 = b;
            mcnt += m_t;
            if (t >= 1 && m_t) {
                const int tag_p = tg[t - 1];
                nsum += transitions[tag_p * Cn + tag_t] + em0[t * Cn + tag_t];
            }
        }
#pragma unroll
        for (int off = 32; off > 0; off >>= 1) {
            nsum += __shfl_xor(nsum, off, 64);
            mcnt += __shfl_xor(mcnt, off, 64);
        }

        // expT column j in registers (coalesced global reads, as in R5).
        float w[Cn];
#pragma unroll
        for (int i = 0; i < Cn; ++i) w[i] = __expf(transitions[i * Cn + j]);

        // t = 0.
        float lp0 = start_t[j] + em[0];
        const float m0 = wave_max64(lp0);
        float log_scale = m0;
        float a_self = __expf(lp0 - m0);     // lane j holds alpha[j]
        float c_pend = 1.0f;                 // deferred renorm scale

        // Ping-pong prologue: P <- group 0 (t=1..4), Q <- group 1 (t=5..8).
        float P[4], Q[4];
#pragma unroll
        for (int k = 0; k < 4; ++k) P[k] = em[(size_t)(1 + k) * Cn];
#pragma unroll
        for (int k = 0; k < 4; ++k) Q[k] = em[(size_t)(5 + k) * Cn];

#define FWD_STEP(k, tt, exk)                                               \
        {                                                                  \
            float s_ = bcast_dot64(a_self, w) * (exk);                     \
            const int t_ = (tt);                                           \
            const unsigned long long bw_ = (t_ < 128)                     \
                ? (t_ < 64 ? bal0 : bal1)                                  \
                : (t_ < 192 ? bal2 : (t_ < 256 ? bal3 : bal4));            \
            if (!((bw_ >> (t_ & 63)) & 1ull)) s_ = a_self;                 \
            if ((k) == 0) { s_ *= c_pend; c_pend = 1.0f; }                 \
            if ((k) == 3) { const float mx_ = wave_max64(s_);              \
                            c_pend = __builtin_amdgcn_rcpf(mx_);           \
                            log_scale += __logf(mx_); }                    \
            a_self = s_;                                                   \
        }

#pragma unroll 1
        for (int i = 0; i < 32; ++i) {       // 32 iters x 2 groups = 256 steps
            // ---- group 2i: use P, then refill P with group 2i+2 ----
            {
                const float ex0 = __expf(P[0]), ex1 = __expf(P[1]);
                const float ex2 = __expf(P[2]), ex3 = __expf(P[3]);
                const int tp = 8 * i + 9;     // <= 257, valid
#pragma unroll
                for (int k = 0; k < 4; ++k) P[k] = em[(size_t)(tp + k) * Cn];
                FWD_STEP(0, 8 * i + 1, ex0)
                FWD_STEP(1, 8 * i + 2, ex1)
                FWD_STEP(2, 8 * i + 3, ex2)
                FWD_STEP(3, 8 * i + 4, ex3)
            }
            // ---- group 2i+1: use Q, then refill Q with group 2i+3 ----
            {
                const float ex0 = __expf(Q[0]), ex1 = __expf(Q[1]);
                const float ex2 = __expf(Q[2]), ex3 = __expf(Q[3]);
                const int tq = 8 * i + 13;    // <= 261 < 512, valid
#pragma unroll
                for (int k = 0; k < 4; ++k) Q[k] = em[(size_t)(tq + k) * Cn];
                FWD_STEP(0, 8 * i + 5, ex0)
                FWD_STEP(1, 8 * i + 6, ex1)
                FWD_STEP(2, 8 * i + 7, ex2)
                FWD_STEP(3, 8 * i + 8, ex3)
            }
        }
#undef FWD_STEP

        a_self *= c_pend;                     // flush pending scale
        ws_alpha[bt * Cn + j] = a_self;       // alpha_256
        if (j == 0) {
            ws_lsF[bt] = log_scale;
            const int t0 = tg[0];
            const int tl = tg[mcnt - 1];
            ws_num[bt] = start_t[t0] + em0[t0] + nsum + end_t[tl];
        }
    } else {
        // ---- ballot-pack mask windows 4..7 (u = 256..511) ----------------
        unsigned long long bal4 = 0, bal5 = 0, bal6 = 0, bal7 = 0;
#pragma unroll
        for (int it = 4; it < 8; ++it) {
            const unsigned long long b = __ballot(mk[it * 64 + j] != 0);
            if      (it == 4) bal4 = b;
            else if (it == 5) bal5 = b;
            else if (it == 6) bal6 = b;
            else              bal7 = b;
        }

        // expT ROW j in registers (backward dot uses rows).
        float w[Cn];
#pragma unroll
        for (int i = 0; i < Cn; ++i) w[i] = __expf(transitions[j * Cn + i]);

        // beta_511 = exp(end - max).
        float lp0 = end_t[j];
        const float m0 = wave_max64(lp0);
        float log_scale = m0;
        float b_self = __expf(lp0 - m0);      // lane j holds beta[j]
        float c_pend = 1.0f;

        // Ping-pong prologue: P <- group 0 (u=511..508), Q <- group 1 (507..504).
        float P[4], Q[4];
#pragma unroll
        for (int k = 0; k < 4; ++k) P[k] = em[(size_t)(Tn - 1 - k) * Cn];
#pragma unroll
        for (int k = 0; k < 4; ++k) Q[k] = em[(size_t)(Tn - 5 - k) * Cn];

#define BWD_STEP(k, uu, exk)                                               \
        {                                                                  \
            const float wval_ = b_self * (exk);                            \
            float s_ = bcast_dot64(wval_, w);                              \
            const int u_ = (uu);                                           \
            const unsigned long long bw_ = (u_ < 384)                      \
                ? (u_ < 320 ? bal4 : bal5)                                 \
                : (u_ < 448 ? bal6 : bal7);                                \
            if (!((bw_ >> (u_ & 63)) & 1ull)) s_ = b_self;                 \
            if ((k) == 0) { s_ *= c_pend; c_pend = 1.0f; }                 \
            if ((k) == 3) { const float mx_ = wave_max64(s_);              \
                            c_pend = __builtin_amdgcn_rcpf(mx_);           \
                            log_scale += __logf(mx_); }                    \
            b_self = s_;                                                   \
        }

#pragma unroll 1
        for (int i = 0; i < 32; ++i) {       // steps s = 8i .. 8i+7 (last skipped)
            // ---- group 2i (s = 8i..8i+3, u = 511-8i-k): use P, refill P ----
            {
                const float ex0 = __expf(P[0]), ex1 = __expf(P[1]);
                const float ex2 = __expf(P[2]), ex3 = __expf(P[3]);
                const int up = 503 - 8 * i;   // group 2i+2; >= 255-3 >= 0
#pragma unroll
                for (int k = 0; k < 4; ++k) P[k] = em[(size_t)(up - k) * Cn];
                BWD_STEP(0, 511 - 8 * i, ex0)
                BWD_STEP(1, 510 - 8 * i, ex1)
                BWD_STEP(2, 509 - 8 * i, ex2)
                BWD_STEP(3, 508 - 8 * i, ex3)
            }
            // ---- group 2i+1 (s = 8i+4..8i+7, u = 507-8i-k): use Q, refill Q ----
            {
                const float ex0 = __expf(Q[0]), ex1 = __expf(Q[1]);
                const float ex2 = __expf(Q[2]), ex3 = __expf(Q[3]);
                const int uq = 499 - 8 * i;   // group 2i+3; >= 248 >= 0
#pragma unroll
                for (int k = 0; k < 4; ++k) Q[k] = em[(size_t)(uq - k) * Cn];
                BWD_STEP(0, 507 - 8 * i, ex0)
                BWD_STEP(1, 506 - 8 * i, ex1)
                BWD_STEP(2, 505 - 8 * i, ex2)
                if (i < 31) {                 // s = 8i+7 == 255 skipped at i==31
                    BWD_STEP(3, 504 - 8 * i, ex3)
                }
            }
        }
#undef BWD_STEP

        b_self *= c_pend;                     // flush pending scale
        ws_beta[bt * Cn + j] = b_self;        // beta_256
        if (j == 0) ws_lsB[bt] = log_scale;
    }
}

// Per chain: denom = lsF + lsB + log(sum_i alpha[i]*beta[i]); mean-reduce.
// 32 blocks x 16 waves; one chain per wave; one atomicAdd per block.
__global__ __launch_bounds__(1024) void crf_combine_kernel(
    const float* __restrict__ ws_alpha,
    const float* __restrict__ ws_beta,
    const float* __restrict__ ws_lsF,
    const float* __restrict__ ws_lsB,
    const float* __restrict__ ws_num,
    float*       __restrict__ out)
{
    const int wv = threadIdx.x >> 6;          // wave 0..15
    const int j  = threadIdx.x & 63;
    const int bt = blockIdx.x * 16 + wv;

    __shared__ float part[16];

    float v = ws_alpha[bt * Cn + j] * ws_beta[bt * Cn + j];
#pragma unroll
    for (int off = 32; off > 0; off >>= 1) v += __shfl_xor(v, off, 64);
    if (j == 0) {
        part[wv] = ws_lsF[bt] + ws_lsB[bt] + __logf(v) - ws_num[bt];
    }
    __syncthreads();
    if (threadIdx.x < 64) {
        float p = (j < 16) ? part[j] : 0.f;
#pragma unroll
        for (int off = 32; off > 0; off >>= 1) p += __shfl_xor(p, off, 64);
        if (j == 0) atomicAdd(out, p * (1.0f / Bn));
    }
}

extern "C" void kernel_launch(void* const* d_in, const int* in_sizes, int n_in,
                              void* d_out, int out_size, void* d_ws, size_t ws_size,
                              hipStream_t stream)
{
    const float* emissions   = (const float*)d_in[0];
    const int*   tags        = (const int*)d_in[1];
    const int*   mask        = (const int*)d_in[2];
    const float* transitions = (const float*)d_in[3];
    const float* start_t     = (const float*)d_in[4];
    const float* end_t       = (const float*)d_in[5];

    float* ws       = (float*)d_ws;
    float* ws_alpha = ws;                       // 512*64
    float* ws_beta  = ws_alpha + Bn * Cn;       // 512*64
    float* ws_lsF   = ws_beta + Bn * Cn;        // 512
    float* ws_lsB   = ws_lsF + Bn;              // 512
    float* ws_num   = ws_lsB + Bn;              // 512

    crf_half_kernel<<<2 * Bn, Cn, 0, stream>>>(emissions, tags, mask, transitions,
                                               start_t, end_t,
                                               ws_alpha, ws_beta, ws_lsF, ws_lsB, ws_num,
                                               (float*)d_out);
    crf_combine_kernel<<<Bn / 16, 1024, 0, stream>>>(ws_alpha, ws_beta, ws_lsF, ws_lsB,
                                                     ws_num, (float*)d_out);
}